// Round 9
// baseline (519.446 us; speedup 1.0000x reference)
//
#include <hip/hip_runtime.h>
#include <hip/hip_bf16.h>
#include <math.h>

// Problem constants (from reference)
#define T_SEQ 1536
#define CDIM  1536
#define HEADS 8
#define DK    64
#define DV    192
#define HK    (HEADS * DK)    // 512
#define HV    (HEADS * DV)    // 1536
#define RWIN  (2 * T_SEQ - 1) // 3071

typedef __attribute__((ext_vector_type(8))) short bf16x8;
typedef __attribute__((ext_vector_type(4))) float f32x4;

__device__ __forceinline__ unsigned short f2bf(float v) {
  __hip_bfloat16 h = __float2bfloat16(v);
  return *reinterpret_cast<unsigned short*>(&h);
}
__device__ __forceinline__ float bf2f(unsigned short u) {
  unsigned int x = ((unsigned int)u) << 16;
  union { unsigned int i; float f; } c; c.i = x; return c.f;
}

// ---------------------------------------------------------------------------
// Elementwise fp32 -> bf16 cast. n multiple of 1024.
// ---------------------------------------------------------------------------
__global__ __launch_bounds__(256) void cast_bf16_kernel(
    const float* __restrict__ in, unsigned short* __restrict__ out, int n)
{
  const int i = (blockIdx.x * 256 + threadIdx.x) * 4;
  if (i >= n) return;
  const float4 v = *reinterpret_cast<const float4*>(&in[i]);
  ushort4 o;
  o.x = f2bf(v.x); o.y = f2bf(v.y); o.z = f2bf(v.z); o.w = f2bf(v.w);
  *reinterpret_cast<ushort4*>(&out[i]) = o;
}

// ---------------------------------------------------------------------------
// Transpose-cast: W[Kd][N] fp32 -> Wt[N][Kd] bf16.
// ---------------------------------------------------------------------------
__global__ __launch_bounds__(256) void tcast_kernel(
    const float* __restrict__ W, unsigned short* __restrict__ Wt, int Kd, int N)
{
  __shared__ float tile[32][33];
  const int n0 = blockIdx.x * 32, k0 = blockIdx.y * 32;
  const int tx = threadIdx.x, ty = threadIdx.y;
  #pragma unroll
  for (int i = 0; i < 32; i += 8)
    tile[ty + i][tx] = W[(size_t)(k0 + ty + i) * N + n0 + tx];
  __syncthreads();
  #pragma unroll
  for (int i = 0; i < 32; i += 8)
    Wt[(size_t)(n0 + ty + i) * Kd + k0 + tx] = f2bf(tile[tx][ty + i]);
}

// ---------------------------------------------------------------------------
// bf16 transpose: vb[b*T+t][HV] -> vt[b][v][t]  (both coalesced via LDS tile)
// ---------------------------------------------------------------------------
__global__ __launch_bounds__(256) void vtrans_kernel(
    const unsigned short* __restrict__ in, unsigned short* __restrict__ out)
{
  __shared__ unsigned short tile[32][33];
  const int v0 = blockIdx.x * 32, t0 = blockIdx.y * 32, b = blockIdx.z;
  const int tx = threadIdx.x, ty = threadIdx.y;
  #pragma unroll
  for (int i = 0; i < 32; i += 8)
    tile[ty + i][tx] = in[(size_t)(b * T_SEQ + t0 + ty + i) * HV + v0 + tx];
  __syncthreads();
  #pragma unroll
  for (int i = 0; i < 32; i += 8)
    out[((size_t)b * HV + v0 + ty + i) * T_SEQ + t0 + tx] = tile[tx][ty + i];
}

// ---------------------------------------------------------------------------
// bf16 MFMA GEMM (R6 HW-validated body). OMODE 0: f32 out (+bias); 1: bf16 out.
// ---------------------------------------------------------------------------
template<int OMODE>
__global__ __launch_bounds__(256) void gemm_bf16_kernel(
    const unsigned short* __restrict__ A, const unsigned short* __restrict__ Bt,
    void* __restrict__ Cp, int M, int N, int Kd, float scale,
    const float* __restrict__ bias)
{
  constexpr int LDK = 40;
  __shared__ unsigned short As[128 * LDK];
  __shared__ unsigned short Bs[128 * LDK];
  const int tid = threadIdx.x;
  const int lane = tid & 63, wave = tid >> 6;
  const int wr = wave >> 1, wc = wave & 1;
  const int m0 = blockIdx.x * 128, n0 = blockIdx.y * 128;

  const int lr = tid >> 2;
  const int lc = (tid & 3) * 8;
  const int frow = lane & 15;
  const int fk = (lane >> 4) * 8;

  f32x4 acc[4][4];
  #pragma unroll
  for (int i = 0; i < 4; ++i)
    #pragma unroll
    for (int j = 0; j < 4; ++j) acc[i][j] = (f32x4){0.f, 0.f, 0.f, 0.f};

  uint4 a0 = *reinterpret_cast<const uint4*>(&A[(size_t)(m0 + lr) * Kd + lc]);
  uint4 a1 = *reinterpret_cast<const uint4*>(&A[(size_t)(m0 + 64 + lr) * Kd + lc]);
  uint4 b0 = *reinterpret_cast<const uint4*>(&Bt[(size_t)(n0 + lr) * Kd + lc]);
  uint4 b1 = *reinterpret_cast<const uint4*>(&Bt[(size_t)(n0 + 64 + lr) * Kd + lc]);

  for (int k0 = 0; k0 < Kd; k0 += 32) {
    __syncthreads();
    *reinterpret_cast<uint4*>(&As[lr * LDK + lc]) = a0;
    *reinterpret_cast<uint4*>(&As[(64 + lr) * LDK + lc]) = a1;
    *reinterpret_cast<uint4*>(&Bs[lr * LDK + lc]) = b0;
    *reinterpret_cast<uint4*>(&Bs[(64 + lr) * LDK + lc]) = b1;
    __syncthreads();
    if (k0 + 32 < Kd) {
      const int kn = k0 + 32;
      a0 = *reinterpret_cast<const uint4*>(&A[(size_t)(m0 + lr) * Kd + kn + lc]);
      a1 = *reinterpret_cast<const uint4*>(&A[(size_t)(m0 + 64 + lr) * Kd + kn + lc]);
      b0 = *reinterpret_cast<const uint4*>(&Bt[(size_t)(n0 + lr) * Kd + kn + lc]);
      b1 = *reinterpret_cast<const uint4*>(&Bt[(size_t)(n0 + 64 + lr) * Kd + kn + lc]);
    }
    bf16x8 af[4], bfr[4];
    #pragma unroll
    for (int mi = 0; mi < 4; ++mi)
      af[mi] = *reinterpret_cast<const bf16x8*>(&As[(wr * 64 + mi * 16 + frow) * LDK + fk]);
    #pragma unroll
    for (int ni = 0; ni < 4; ++ni)
      bfr[ni] = *reinterpret_cast<const bf16x8*>(&Bs[(wc * 64 + ni * 16 + frow) * LDK + fk]);
    #pragma unroll
    for (int mi = 0; mi < 4; ++mi)
      #pragma unroll
      for (int ni = 0; ni < 4; ++ni)
        acc[mi][ni] = __builtin_amdgcn_mfma_f32_16x16x32_bf16(af[mi], bfr[ni], acc[mi][ni], 0, 0, 0);
  }

  const int er = (lane >> 4) * 4;
  #pragma unroll
  for (int mi = 0; mi < 4; ++mi)
    #pragma unroll
    for (int ni = 0; ni < 4; ++ni) {
      const int n = n0 + wc * 64 + ni * 16 + frow;
      #pragma unroll
      for (int r = 0; r < 4; ++r) {
        const int m = m0 + wr * 64 + mi * 16 + er + r;
        float v = acc[mi][ni][r] * scale;
        if constexpr (OMODE == 0) {
          if (bias != nullptr) v += bias[n];
          ((float*)Cp)[(size_t)m * N + n] = v;
        } else {
          ((unsigned short*)Cp)[(size_t)m * N + n] = f2bf(v);
        }
      }
    }
}

// ---------------------------------------------------------------------------
// r_k (bf16 out): rk[h][r][kk] = sum_f pos[r,f] * Wrk[f, h*64+kk]
// ---------------------------------------------------------------------------
__global__ __launch_bounds__(512) void rk_kernel(
    const float* __restrict__ Wrk, unsigned short* __restrict__ rk)
{
  const int r = blockIdx.x;
  const int t = threadIdx.x;
  __shared__ float pos[64];

  if (t < 64) {
    const double d = (double)(r - (T_SEQ - 1));
    const int j = t & 31;
    const double pr = exp(log((double)(T_SEQ + 1)) / 32.0);
    const double w = pow(pr, (double)(j + 1)) - 1.0;
    const float emb = (w > fabs(d)) ? 1.0f : 0.0f;
    const float sgn = (d > 0.0) ? 1.f : ((d < 0.0) ? -1.f : 0.f);
    pos[t] = (t < 32) ? emb : sgn * emb;
  }
  __syncthreads();

  float acc = 0.f;
  #pragma unroll 8
  for (int f = 0; f < 64; ++f) acc = fmaf(pos[f], Wrk[f * HK + t], acc);

  const int h = t >> 6, kk = t & 63;
  rk[((size_t)h * RWIN + r) * DK + kk] = f2bf(acc);
}

// ---------------------------------------------------------------------------
// MFMA flash attention, barrier-free. 1-D grid 384 blocks, XCD-swizzled so
// each XCD owns all 24 q-tiles of 6 consecutive (h,b) -> K/V/rk L2-hot.
// K/V/rk fragments are read DIRECTLY from global (L2-fit; staging was pure
// overhead: 71KB LDS -> 2 blk/CU + 2 barriers/tile + 8.3M bank conflicts).
// Rbuf/Plds are wave-local -> no __syncthreads anywhere in the loop.
// LDS 26.1KB -> 6 blocks/CU (occupancy cap 75%).
// ---------------------------------------------------------------------------
__global__ __launch_bounds__(256, 4) void attn_mfma_kernel(
    const float* __restrict__ qf, const unsigned short* __restrict__ kb,
    const unsigned short* __restrict__ vt, const unsigned short* __restrict__ rkb,
    const float* __restrict__ rwb, const float* __restrict__ rrb,
    unsigned short* __restrict__ ab)
{
  const int bid = blockIdx.x;                 // 0..383
  const int wk = (bid & 7) * 48 + (bid >> 3); // XCD swizzle (384%8==0, bijective)
  const int it = wk % 24;
  const int h  = (wk / 24) & 7;
  const int b  = wk / 192;
  const int i0 = it * 64;
  const int tid = threadIdx.x, lane = tid & 63, wv = tid >> 6;
  const int cl = lane & 15, g4 = 4 * (lane >> 4), kb8 = 8 * (lane >> 4);

  __shared__ unsigned short Rbuf[64][132];   // 16896 B (128-slot ring + pad)
  __shared__ unsigned short Plds[64][72];    //  9216 B

  // ---- Q fragments (A-layout: row=lane&15 within wave's 16, k=8*(lane>>4)+e)
  bf16x8 qwf[2], qrf[2];
  {
    const int qrow = b * T_SEQ + i0 + 16 * wv + cl;
    const float* qp = &qf[(size_t)qrow * HK + h * DK];
    #pragma unroll
    for (int kf = 0; kf < 2; ++kf) {
      bf16x8 tw, tr;
      #pragma unroll
      for (int e = 0; e < 8; ++e) {
        const int k = kb8 + 32 * kf + e;
        const float qv = qp[k];                  // already scaled by 0.125
        tw[e] = (short)f2bf(qv + rwb[h * DK + k]);
        tr[e] = (short)f2bf(qv + rrb[h * DK + k]);
      }
      qwf[kf] = tw; qrf[kf] = tr;
    }
  }

  // ---- rel band (64 cols at rk rows [base, base+64)) -> ring (wave-local) ----
  auto computeR = [&](int base) {
    #pragma unroll
    for (int f = 0; f < 4; ++f) {
      f32x4 rr = (f32x4){0.f, 0.f, 0.f, 0.f};
      #pragma unroll
      for (int ks = 0; ks < 2; ++ks) {
        int row = base + 16 * f + cl;
        row = row < 0 ? 0 : row;                 // rho=-1 slot written, never read
        const bf16x8 bfrag = *reinterpret_cast<const bf16x8*>(
            &rkb[((size_t)h * RWIN + row) * DK + kb8 + 32 * ks]);
        rr = __builtin_amdgcn_mfma_f32_16x16x32_bf16(qrf[ks], bfrag, rr, 0, 0, 0);
      }
      const int irow = 16 * wv + g4;
      const int slot = (base + 16 * f + cl) & 127;
      #pragma unroll
      for (int r = 0; r < 4; ++r)
        Rbuf[irow + r][slot] = f2bf(rr[r]);
    }
  };

  float mrun[4] = {-1e30f, -1e30f, -1e30f, -1e30f};
  float lrun[4] = {0.f, 0.f, 0.f, 0.f};
  f32x4 o[12];
  #pragma unroll
  for (int vf = 0; vf < 12; ++vf) o[vf] = (f32x4){0.f, 0.f, 0.f, 0.f};

  const int D0 = T_SEQ - 1 - i0;
  computeR(D0 - 64);                             // prologue band
  int Dj = D0;

  const unsigned short* kbase = &kb[(size_t)(b * T_SEQ) * HK + h * DK];
  const unsigned short* vbase = &vt[((size_t)b * HV + h * DV) * T_SEQ];

  for (int jt = 0; jt < T_SEQ / 64; ++jt) {
    const int j0 = jt * 64;
    computeR(Dj);                                // new 64 ring cols [Dj, Dj+63]

    // content: S = qw @ K^T  (B-frags: contiguous 16B global, L2-hot)
    f32x4 s[4];
    #pragma unroll
    for (int f = 0; f < 4; ++f) {
      s[f] = (f32x4){0.f, 0.f, 0.f, 0.f};
      #pragma unroll
      for (int ks = 0; ks < 2; ++ks) {
        const bf16x8 kfrag = *reinterpret_cast<const bf16x8*>(
            &kbase[(size_t)(j0 + 16 * f + cl) * HK + kb8 + 32 * ks]);
        s[f] = __builtin_amdgcn_mfma_f32_16x16x32_bf16(qwf[ks], kfrag, s[f], 0, 0, 0);
      }
    }
    // rel gather-add: rho = Dj + j' - i'
    #pragma unroll
    for (int f = 0; f < 4; ++f)
      #pragma unroll
      for (int r = 0; r < 4; ++r) {
        const int iloc = 16 * wv + g4 + r;
        const int slot = (Dj + 16 * f + cl - iloc) & 127;
        s[f][r] += bf2f(Rbuf[iloc][slot]);
      }
    // online softmax (rows lane-local across S and O frags)
    #pragma unroll
    for (int r = 0; r < 4; ++r) {
      float mx = fmaxf(fmaxf(s[0][r], s[1][r]), fmaxf(s[2][r], s[3][r]));
      mx = fmaxf(mx, __shfl_xor(mx, 1));
      mx = fmaxf(mx, __shfl_xor(mx, 2));
      mx = fmaxf(mx, __shfl_xor(mx, 4));
      mx = fmaxf(mx, __shfl_xor(mx, 8));
      const float mnew = fmaxf(mrun[r], mx);
      const float fac = __expf(mrun[r] - mnew);
      mrun[r] = mnew;
      float ps = 0.f;
      #pragma unroll
      for (int f = 0; f < 4; ++f) {
        const float p = __expf(s[f][r] - mnew);
        ps += p;
        Plds[16 * wv + g4 + r][16 * f + cl] = f2bf(p);
      }
      ps += __shfl_xor(ps, 1);
      ps += __shfl_xor(ps, 2);
      ps += __shfl_xor(ps, 4);
      ps += __shfl_xor(ps, 8);
      lrun[r] = lrun[r] * fac + ps;
      #pragma unroll
      for (int vf = 0; vf < 12; ++vf) o[vf][r] *= fac;
    }
    // PV: O += P @ V^T  (V-frags: contiguous 16B global along t, L2-hot)
    __builtin_amdgcn_s_setprio(1);
    #pragma unroll
    for (int ks = 0; ks < 2; ++ks) {
      const bf16x8 pfrag = *reinterpret_cast<const bf16x8*>(
          &Plds[16 * wv + cl][kb8 + 32 * ks]);
      #pragma unroll
      for (int vf = 0; vf < 12; ++vf) {
        const bf16x8 vfrag = *reinterpret_cast<const bf16x8*>(
            &vbase[(size_t)(16 * vf + cl) * T_SEQ + j0 + kb8 + 32 * ks]);
        o[vf] = __builtin_amdgcn_mfma_f32_16x16x32_bf16(pfrag, vfrag, o[vf], 0, 0, 0);
      }
    }
    __builtin_amdgcn_s_setprio(0);
    Dj += 64;
  }

  // epilogue: O / l -> ab bf16
  #pragma unroll
  for (int r = 0; r < 4; ++r) {
    const float inv = 1.f / lrun[r];
    const size_t gi = (size_t)(b * T_SEQ + i0 + 16 * wv + g4 + r);
    #pragma unroll
    for (int vf = 0; vf < 12; ++vf) {
      const int v = 16 * vf + cl;
      ab[gi * HV + h * DV + v] = f2bf(o[vf][r] * inv);
    }
  }
}

// ---------------------------------------------------------------------------
extern "C" void kernel_launch(void* const* d_in, const int* in_sizes, int n_in,
                              void* d_out, int out_size, void* d_ws, size_t ws_size,
                              hipStream_t stream) {
  const float* x   = (const float*)d_in[0];
  const float* Wq  = (const float*)d_in[1];
  const float* Wk  = (const float*)d_in[2];
  const float* Wv  = (const float*)d_in[3];
  const float* Wrk = (const float*)d_in[4];
  const float* rwb = (const float*)d_in[5];
  const float* rrb = (const float*)d_in[6];
  const float* Wo  = (const float*)d_in[7];
  const float* bo  = (const float*)d_in[8];
  float* out = (float*)d_out;

  const int BT = 2 * T_SEQ;   // 3072

  // Workspace: 53,476,352 B total (== R7/R8 proven footprint)
  char* w = (char*)d_ws;
  float* qf            = (float*)w;          w += (size_t)BT * HK * 4;        // q f32 scaled
  unsigned short* kbuf = (unsigned short*)w; w += (size_t)BT * HK * 2;        // k bf16 [t][hk]
  unsigned short* vb   = (unsigned short*)w; w += (size_t)BT * HV * 2;        // v bf16 [t][hv]
  unsigned short* vtb  = (unsigned short*)w; w += (size_t)2 * HV * T_SEQ * 2; // V^T bf16 [b][v][t]
  unsigned short* rkb  = (unsigned short*)w; w += (size_t)HEADS * RWIN * DK * 2;
  unsigned short* xb   = (unsigned short*)w; w += (size_t)BT * CDIM * 2;      // x bf16, later ab
  unsigned short* Wqt  = (unsigned short*)w; w += (size_t)HK * CDIM * 2;
  unsigned short* Wkt  = (unsigned short*)w; w += (size_t)HK * CDIM * 2;
  unsigned short* Wvt  = (unsigned short*)w; w += (size_t)HV * CDIM * 2;
  unsigned short* Wot  = (unsigned short*)w; w += (size_t)HV * CDIM * 2;
  unsigned short* ab   = xb;   // x dead after v GEMM; attn output reuses xb

  const int nx = BT * CDIM;

  cast_bf16_kernel<<<nx / 1024, 256, 0, stream>>>(x, xb, nx);
  tcast_kernel<<<dim3(HK / 32, CDIM / 32), dim3(32, 8), 0, stream>>>(Wq, Wqt, CDIM, HK);
  tcast_kernel<<<dim3(HK / 32, CDIM / 32), dim3(32, 8), 0, stream>>>(Wk, Wkt, CDIM, HK);
  tcast_kernel<<<dim3(HV / 32, CDIM / 32), dim3(32, 8), 0, stream>>>(Wv, Wvt, CDIM, HV);
  tcast_kernel<<<dim3(HV / 32, CDIM / 32), dim3(32, 8), 0, stream>>>(Wo, Wot, CDIM, HV);

  gemm_bf16_kernel<0><<<dim3(BT / 128, HK / 128), 256, 0, stream>>>(
      xb, Wqt, qf, BT, HK, CDIM, 0.125f, nullptr);
  gemm_bf16_kernel<1><<<dim3(BT / 128, HK / 128), 256, 0, stream>>>(
      xb, Wkt, kbuf, BT, HK, CDIM, 1.0f, nullptr);
  gemm_bf16_kernel<1><<<dim3(BT / 128, HV / 128), 256, 0, stream>>>(
      xb, Wvt, vb, BT, HV, CDIM, 1.0f, nullptr);

  // coalesced bf16 transpose vb[t][hv] -> vt[b][v][t]
  vtrans_kernel<<<dim3(HV / 32, T_SEQ / 32, 2), dim3(32, 8), 0, stream>>>(vb, vtb);

  rk_kernel<<<RWIN, 512, 0, stream>>>(Wrk, rkb);

  attn_mfma_kernel<<<384, 256, 0, stream>>>(
      qf, kbuf, vtb, rkb, rwb, rrb, ab);

  gemm_bf16_kernel<0><<<dim3(BT / 128, HV / 128), 256, 0, stream>>>(
      ab, Wot, out, BT, HV, CDIM, 1.0f, bo);
}

// Round 11
// 411.203 us; speedup vs baseline: 1.2632x; 1.2632x over previous
//
#include <hip/hip_runtime.h>
#include <hip/hip_bf16.h>
#include <math.h>

// Problem constants (from reference)
#define T_SEQ 1536
#define CDIM  1536
#define HEADS 8
#define DK    64
#define DV    192
#define HK    (HEADS * DK)    // 512
#define HV    (HEADS * DV)    // 1536
#define RWIN  (2 * T_SEQ - 1) // 3071

typedef __attribute__((ext_vector_type(8))) short bf16x8;
typedef __attribute__((ext_vector_type(4))) float f32x4;

__device__ __forceinline__ unsigned short f2bf(float v) {
  __hip_bfloat16 h = __float2bfloat16(v);
  return *reinterpret_cast<unsigned short*>(&h);
}
__device__ __forceinline__ float bf2f(unsigned short u) {
  unsigned int x = ((unsigned int)u) << 16;
  union { unsigned int i; float f; } c; c.i = x; return c.f;
}

// ---------------------------------------------------------------------------
__global__ __launch_bounds__(256) void cast_bf16_kernel(
    const float* __restrict__ in, unsigned short* __restrict__ out, int n)
{
  const int i = (blockIdx.x * 256 + threadIdx.x) * 4;
  if (i >= n) return;
  const float4 v = *reinterpret_cast<const float4*>(&in[i]);
  ushort4 o;
  o.x = f2bf(v.x); o.y = f2bf(v.y); o.z = f2bf(v.z); o.w = f2bf(v.w);
  *reinterpret_cast<ushort4*>(&out[i]) = o;
}

// ---------------------------------------------------------------------------
__global__ __launch_bounds__(256) void tcast_kernel(
    const float* __restrict__ W, unsigned short* __restrict__ Wt, int Kd, int N)
{
  __shared__ float tile[32][33];
  const int n0 = blockIdx.x * 32, k0 = blockIdx.y * 32;
  const int tx = threadIdx.x, ty = threadIdx.y;
  #pragma unroll
  for (int i = 0; i < 32; i += 8)
    tile[ty + i][tx] = W[(size_t)(k0 + ty + i) * N + n0 + tx];
  __syncthreads();
  #pragma unroll
  for (int i = 0; i < 32; i += 8)
    Wt[(size_t)(n0 + ty + i) * Kd + k0 + tx] = f2bf(tile[tx][ty + i]);
}

// ---------------------------------------------------------------------------
// bf16 transpose: vb[b*T+t][HV] -> vt[b][v][t]
// ---------------------------------------------------------------------------
__global__ __launch_bounds__(256) void vtrans_kernel(
    const unsigned short* __restrict__ in, unsigned short* __restrict__ out)
{
  __shared__ unsigned short tile[32][33];
  const int v0 = blockIdx.x * 32, t0 = blockIdx.y * 32, b = blockIdx.z;
  const int tx = threadIdx.x, ty = threadIdx.y;
  #pragma unroll
  for (int i = 0; i < 32; i += 8)
    tile[ty + i][tx] = in[(size_t)(b * T_SEQ + t0 + ty + i) * HV + v0 + tx];
  __syncthreads();
  #pragma unroll
  for (int i = 0; i < 32; i += 8)
    out[((size_t)b * HV + v0 + ty + i) * T_SEQ + t0 + tx] = tile[tx][ty + i];
}

// ---------------------------------------------------------------------------
// Fused QKV GEMM: A[M][1536] bf16 @ Bt[2560][1536]^T. Bt = Wqt|Wkt|Wvt
// (contiguous). Epilogue routes block-uniform n-range:
// n<512 -> qf f32 *0.125 ; n<1024 -> kbuf bf16 ; else -> vb bf16.
// Body = R6 HW-validated GEMM (reg-prefetch rotation, LDK=40).
// ---------------------------------------------------------------------------
__global__ __launch_bounds__(256) void gemm_qkv_kernel(
    const unsigned short* __restrict__ A, const unsigned short* __restrict__ Bt,
    float* __restrict__ qf, unsigned short* __restrict__ kbuf,
    unsigned short* __restrict__ vb, int M, int Kd)
{
  constexpr int LDK = 40;
  __shared__ unsigned short As[128 * LDK];
  __shared__ unsigned short Bs[128 * LDK];
  const int tid = threadIdx.x;
  const int lane = tid & 63, wave = tid >> 6;
  const int wr = wave >> 1, wc = wave & 1;
  const int m0 = blockIdx.x * 128, n0 = blockIdx.y * 128;

  const int lr = tid >> 2;
  const int lc = (tid & 3) * 8;
  const int frow = lane & 15;
  const int fk = (lane >> 4) * 8;

  f32x4 acc[4][4];
  #pragma unroll
  for (int i = 0; i < 4; ++i)
    #pragma unroll
    for (int j = 0; j < 4; ++j) acc[i][j] = (f32x4){0.f, 0.f, 0.f, 0.f};

  uint4 a0 = *reinterpret_cast<const uint4*>(&A[(size_t)(m0 + lr) * Kd + lc]);
  uint4 a1 = *reinterpret_cast<const uint4*>(&A[(size_t)(m0 + 64 + lr) * Kd + lc]);
  uint4 b0 = *reinterpret_cast<const uint4*>(&Bt[(size_t)(n0 + lr) * Kd + lc]);
  uint4 b1 = *reinterpret_cast<const uint4*>(&Bt[(size_t)(n0 + 64 + lr) * Kd + lc]);

  for (int k0 = 0; k0 < Kd; k0 += 32) {
    __syncthreads();
    *reinterpret_cast<uint4*>(&As[lr * LDK + lc]) = a0;
    *reinterpret_cast<uint4*>(&As[(64 + lr) * LDK + lc]) = a1;
    *reinterpret_cast<uint4*>(&Bs[lr * LDK + lc]) = b0;
    *reinterpret_cast<uint4*>(&Bs[(64 + lr) * LDK + lc]) = b1;
    __syncthreads();
    if (k0 + 32 < Kd) {
      const int kn = k0 + 32;
      a0 = *reinterpret_cast<const uint4*>(&A[(size_t)(m0 + lr) * Kd + kn + lc]);
      a1 = *reinterpret_cast<const uint4*>(&A[(size_t)(m0 + 64 + lr) * Kd + kn + lc]);
      b0 = *reinterpret_cast<const uint4*>(&Bt[(size_t)(n0 + lr) * Kd + kn + lc]);
      b1 = *reinterpret_cast<const uint4*>(&Bt[(size_t)(n0 + 64 + lr) * Kd + kn + lc]);
    }
    bf16x8 af[4], bfr[4];
    #pragma unroll
    for (int mi = 0; mi < 4; ++mi)
      af[mi] = *reinterpret_cast<const bf16x8*>(&As[(wr * 64 + mi * 16 + frow) * LDK + fk]);
    #pragma unroll
    for (int ni = 0; ni < 4; ++ni)
      bfr[ni] = *reinterpret_cast<const bf16x8*>(&Bs[(wc * 64 + ni * 16 + frow) * LDK + fk]);
    #pragma unroll
    for (int mi = 0; mi < 4; ++mi)
      #pragma unroll
      for (int ni = 0; ni < 4; ++ni)
        acc[mi][ni] = __builtin_amdgcn_mfma_f32_16x16x32_bf16(af[mi], bfr[ni], acc[mi][ni], 0, 0, 0);
  }

  const int er = (lane >> 4) * 4;
  #pragma unroll
  for (int mi = 0; mi < 4; ++mi)
    #pragma unroll
    for (int ni = 0; ni < 4; ++ni) {
      const int n = n0 + wc * 64 + ni * 16 + frow;
      #pragma unroll
      for (int r = 0; r < 4; ++r) {
        const int m = m0 + wr * 64 + mi * 16 + er + r;
        const float v = acc[mi][ni][r];
        if (n < HK) {
          qf[(size_t)m * HK + n] = v * 0.125f;
        } else if (n < 2 * HK) {
          kbuf[(size_t)m * HK + (n - HK)] = f2bf(v);
        } else {
          vb[(size_t)m * HV + (n - 2 * HK)] = f2bf(v);
        }
      }
    }
}

// ---------------------------------------------------------------------------
// Plain bf16 GEMM for Wo: f32 out (+bias).
// ---------------------------------------------------------------------------
__global__ __launch_bounds__(256) void gemm_bf16_kernel(
    const unsigned short* __restrict__ A, const unsigned short* __restrict__ Bt,
    float* __restrict__ C, int M, int N, int Kd, float scale,
    const float* __restrict__ bias)
{
  constexpr int LDK = 40;
  __shared__ unsigned short As[128 * LDK];
  __shared__ unsigned short Bs[128 * LDK];
  const int tid = threadIdx.x;
  const int lane = tid & 63, wave = tid >> 6;
  const int wr = wave >> 1, wc = wave & 1;
  const int m0 = blockIdx.x * 128, n0 = blockIdx.y * 128;

  const int lr = tid >> 2;
  const int lc = (tid & 3) * 8;
  const int frow = lane & 15;
  const int fk = (lane >> 4) * 8;

  f32x4 acc[4][4];
  #pragma unroll
  for (int i = 0; i < 4; ++i)
    #pragma unroll
    for (int j = 0; j < 4; ++j) acc[i][j] = (f32x4){0.f, 0.f, 0.f, 0.f};

  uint4 a0 = *reinterpret_cast<const uint4*>(&A[(size_t)(m0 + lr) * Kd + lc]);
  uint4 a1 = *reinterpret_cast<const uint4*>(&A[(size_t)(m0 + 64 + lr) * Kd + lc]);
  uint4 b0 = *reinterpret_cast<const uint4*>(&Bt[(size_t)(n0 + lr) * Kd + lc]);
  uint4 b1 = *reinterpret_cast<const uint4*>(&Bt[(size_t)(n0 + 64 + lr) * Kd + lc]);

  for (int k0 = 0; k0 < Kd; k0 += 32) {
    __syncthreads();
    *reinterpret_cast<uint4*>(&As[lr * LDK + lc]) = a0;
    *reinterpret_cast<uint4*>(&As[(64 + lr) * LDK + lc]) = a1;
    *reinterpret_cast<uint4*>(&Bs[lr * LDK + lc]) = b0;
    *reinterpret_cast<uint4*>(&Bs[(64 + lr) * LDK + lc]) = b1;
    __syncthreads();
    if (k0 + 32 < Kd) {
      const int kn = k0 + 32;
      a0 = *reinterpret_cast<const uint4*>(&A[(size_t)(m0 + lr) * Kd + kn + lc]);
      a1 = *reinterpret_cast<const uint4*>(&A[(size_t)(m0 + 64 + lr) * Kd + kn + lc]);
      b0 = *reinterpret_cast<const uint4*>(&Bt[(size_t)(n0 + lr) * Kd + kn + lc]);
      b1 = *reinterpret_cast<const uint4*>(&Bt[(size_t)(n0 + 64 + lr) * Kd + kn + lc]);
    }
    bf16x8 af[4], bfr[4];
    #pragma unroll
    for (int mi = 0; mi < 4; ++mi)
      af[mi] = *reinterpret_cast<const bf16x8*>(&As[(wr * 64 + mi * 16 + frow) * LDK + fk]);
    #pragma unroll
    for (int ni = 0; ni < 4; ++ni)
      bfr[ni] = *reinterpret_cast<const bf16x8*>(&Bs[(wc * 64 + ni * 16 + frow) * LDK + fk]);
    #pragma unroll
    for (int mi = 0; mi < 4; ++mi)
      #pragma unroll
      for (int ni = 0; ni < 4; ++ni)
        acc[mi][ni] = __builtin_amdgcn_mfma_f32_16x16x32_bf16(af[mi], bfr[ni], acc[mi][ni], 0, 0, 0);
  }

  const int er = (lane >> 4) * 4;
  #pragma unroll
  for (int mi = 0; mi < 4; ++mi)
    #pragma unroll
    for (int ni = 0; ni < 4; ++ni) {
      const int n = n0 + wc * 64 + ni * 16 + frow;
      #pragma unroll
      for (int r = 0; r < 4; ++r) {
        const int m = m0 + wr * 64 + mi * 16 + er + r;
        float v = acc[mi][ni][r] * scale;
        if (bias != nullptr) v += bias[n];
        C[(size_t)m * N + n] = v;
      }
    }
}

// ---------------------------------------------------------------------------
__global__ __launch_bounds__(512) void rk_kernel(
    const float* __restrict__ Wrk, unsigned short* __restrict__ rk)
{
  const int r = blockIdx.x;
  const int t = threadIdx.x;
  __shared__ float pos[64];

  if (t < 64) {
    const double d = (double)(r - (T_SEQ - 1));
    const int j = t & 31;
    const double pr = exp(log((double)(T_SEQ + 1)) / 32.0);
    const double w = pow(pr, (double)(j + 1)) - 1.0;
    const float emb = (w > fabs(d)) ? 1.0f : 0.0f;
    const float sgn = (d > 0.0) ? 1.f : ((d < 0.0) ? -1.f : 0.f);
    pos[t] = (t < 32) ? emb : sgn * emb;
  }
  __syncthreads();

  float acc = 0.f;
  #pragma unroll 8
  for (int f = 0; f < 64; ++f) acc = fmaf(pos[f], Wrk[f * HK + t], acc);

  const int h = t >> 6, kk = t & 63;
  rk[((size_t)h * RWIN + r) * DK + kk] = f2bf(acc);
}

// ---------------------------------------------------------------------------
// KV-split MFMA flash attention. Grid 768 = 2 splits x 384 q-tiles; exactly
// 3 blocks/CU -> 12 waves/CU (2x R9's TLP; R9 post-mortem: grid=384 was the
// occupancy binder, not LDS). Each block: 64 q-rows, 12 kv-tiles (half range).
// Writes UNNORMALIZED O (bf16) + (m,l) per (row,h); merge kernel combines.
// XCD swizzle groups (b,h,split) per XCD for K/V/rk L2 locality.
// ---------------------------------------------------------------------------
__global__ __launch_bounds__(256, 4) void attn_mfma_kernel(
    const float* __restrict__ qf, const unsigned short* __restrict__ kb,
    const unsigned short* __restrict__ vt, const unsigned short* __restrict__ rkb,
    const float* __restrict__ rwb, const float* __restrict__ rrb,
    unsigned short* __restrict__ pO0, unsigned short* __restrict__ pO1,
    float2* __restrict__ ml0, float2* __restrict__ ml1)
{
  const int bid = blockIdx.x;                  // 0..767
  const int wk = (bid & 7) * 96 + (bid >> 3);  // XCD swizzle (768%8==0)
  const int it = wk % 24;
  const int g  = wk / 24;                      // 0..31
  const int split = g & 1;
  const int h  = (g >> 1) & 7;
  const int b  = g >> 4;
  const int i0 = it * 64;
  const int j0base = split * (T_SEQ / 2);      // 0 or 768
  const int tid = threadIdx.x, lane = tid & 63, wv = tid >> 6;
  const int cl = lane & 15, g4 = 4 * (lane >> 4), kb8 = 8 * (lane >> 4);

  __shared__ unsigned short Rbuf[64][132];   // 16896 B (128-slot ring + pad)
  __shared__ unsigned short Plds[64][72];    //  9216 B

  // ---- Q fragments ----
  bf16x8 qwf[2], qrf[2];
  {
    const int qrow = b * T_SEQ + i0 + 16 * wv + cl;
    const float* qp = &qf[(size_t)qrow * HK + h * DK];
    #pragma unroll
    for (int kf = 0; kf < 2; ++kf) {
      bf16x8 tw, tr;
      #pragma unroll
      for (int e = 0; e < 8; ++e) {
        const int k = kb8 + 32 * kf + e;
        const float qv = qp[k];
        tw[e] = (short)f2bf(qv + rwb[h * DK + k]);
        tr[e] = (short)f2bf(qv + rrb[h * DK + k]);
      }
      qwf[kf] = tw; qrf[kf] = tr;
    }
  }

  auto computeR = [&](int base) {
    #pragma unroll
    for (int f = 0; f < 4; ++f) {
      f32x4 rr = (f32x4){0.f, 0.f, 0.f, 0.f};
      #pragma unroll
      for (int ks = 0; ks < 2; ++ks) {
        int row = base + 16 * f + cl;
        row = row < 0 ? 0 : row;               // rho<0 slots written, never read
        const bf16x8 bfrag = *reinterpret_cast<const bf16x8*>(
            &rkb[((size_t)h * RWIN + row) * DK + kb8 + 32 * ks]);
        rr = __builtin_amdgcn_mfma_f32_16x16x32_bf16(qrf[ks], bfrag, rr, 0, 0, 0);
      }
      const int irow = 16 * wv + g4;
      const int slot = (base + 16 * f + cl) & 127;
      #pragma unroll
      for (int r = 0; r < 4; ++r)
        Rbuf[irow + r][slot] = f2bf(rr[r]);
    }
  };

  float mrun[4] = {-1e30f, -1e30f, -1e30f, -1e30f};
  float lrun[4] = {0.f, 0.f, 0.f, 0.f};
  f32x4 o[12];
  #pragma unroll
  for (int vf = 0; vf < 12; ++vf) o[vf] = (f32x4){0.f, 0.f, 0.f, 0.f};

  int Dj = T_SEQ - 1 - i0 + j0base;
  computeR(Dj - 64);                           // prologue band

  const unsigned short* kbase = &kb[(size_t)(b * T_SEQ) * HK + h * DK];
  const unsigned short* vbase = &vt[((size_t)b * HV + h * DV) * T_SEQ];

  for (int jt = 0; jt < 12; ++jt) {
    const int j0 = j0base + jt * 64;
    computeR(Dj);

    f32x4 s[4];
    #pragma unroll
    for (int f = 0; f < 4; ++f) {
      s[f] = (f32x4){0.f, 0.f, 0.f, 0.f};
      #pragma unroll
      for (int ks = 0; ks < 2; ++ks) {
        const bf16x8 kfrag = *reinterpret_cast<const bf16x8*>(
            &kbase[(size_t)(j0 + 16 * f + cl) * HK + kb8 + 32 * ks]);
        s[f] = __builtin_amdgcn_mfma_f32_16x16x32_bf16(qwf[ks], kfrag, s[f], 0, 0, 0);
      }
    }
    #pragma unroll
    for (int f = 0; f < 4; ++f)
      #pragma unroll
      for (int r = 0; r < 4; ++r) {
        const int iloc = 16 * wv + g4 + r;
        const int slot = (Dj + 16 * f + cl - iloc) & 127;
        s[f][r] += bf2f(Rbuf[iloc][slot]);
      }
    #pragma unroll
    for (int r = 0; r < 4; ++r) {
      float mx = fmaxf(fmaxf(s[0][r], s[1][r]), fmaxf(s[2][r], s[3][r]));
      mx = fmaxf(mx, __shfl_xor(mx, 1));
      mx = fmaxf(mx, __shfl_xor(mx, 2));
      mx = fmaxf(mx, __shfl_xor(mx, 4));
      mx = fmaxf(mx, __shfl_xor(mx, 8));
      const float mnew = fmaxf(mrun[r], mx);
      const float fac = __expf(mrun[r] - mnew);
      mrun[r] = mnew;
      float ps = 0.f;
      #pragma unroll
      for (int f = 0; f < 4; ++f) {
        const float p = __expf(s[f][r] - mnew);
        ps += p;
        Plds[16 * wv + g4 + r][16 * f + cl] = f2bf(p);
      }
      ps += __shfl_xor(ps, 1);
      ps += __shfl_xor(ps, 2);
      ps += __shfl_xor(ps, 4);
      ps += __shfl_xor(ps, 8);
      lrun[r] = lrun[r] * fac + ps;
      #pragma unroll
      for (int vf = 0; vf < 12; ++vf) o[vf][r] *= fac;
    }
    __builtin_amdgcn_s_setprio(1);
    #pragma unroll
    for (int ks = 0; ks < 2; ++ks) {
      const bf16x8 pfrag = *reinterpret_cast<const bf16x8*>(
          &Plds[16 * wv + cl][kb8 + 32 * ks]);
      #pragma unroll
      for (int vf = 0; vf < 12; ++vf) {
        const bf16x8 vfrag = *reinterpret_cast<const bf16x8*>(
            &vbase[(size_t)(16 * vf + cl) * T_SEQ + j0 + kb8 + 32 * ks]);
        o[vf] = __builtin_amdgcn_mfma_f32_16x16x32_bf16(pfrag, vfrag, o[vf], 0, 0, 0);
      }
    }
    __builtin_amdgcn_s_setprio(0);
    Dj += 64;
  }

  // epilogue: unnormalized O + (m,l)
  unsigned short* pO = split ? pO1 : pO0;
  float2* ml = split ? ml1 : ml0;
  #pragma unroll
  for (int r = 0; r < 4; ++r) {
    const size_t gi = (size_t)(b * T_SEQ + i0 + 16 * wv + g4 + r);
    #pragma unroll
    for (int vf = 0; vf < 12; ++vf)
      pO[gi * HV + h * DV + 16 * vf + cl] = f2bf(o[vf][r]);
    if (cl == 0) ml[gi * HEADS + h] = make_float2(mrun[r], lrun[r]);
  }
}

// ---------------------------------------------------------------------------
// Merge 2 KV-split partials -> ab (in-place over pO0). 1 block per row,
// 192 threads x 8 cols.
// ---------------------------------------------------------------------------
__global__ __launch_bounds__(192) void merge_kernel(
    unsigned short* __restrict__ pO0, const unsigned short* __restrict__ pO1,
    const float2* __restrict__ ml0, const float2* __restrict__ ml1)
{
  const int gi = blockIdx.x;
  const int col = threadIdx.x * 8;
  const int h = col / DV;
  const float2 a = ml0[(size_t)gi * HEADS + h];
  const float2 c = ml1[(size_t)gi * HEADS + h];
  const float ms = fmaxf(a.x, c.x);
  float f0 = __expf(a.x - ms), f1 = __expf(c.x - ms);
  const float inv = 1.f / (a.y * f0 + c.y * f1);
  f0 *= inv; f1 *= inv;
  ushort4 u0[2], u1[2];
  *reinterpret_cast<uint4*>(u0) = *reinterpret_cast<const uint4*>(&pO0[(size_t)gi * HV + col]);
  *reinterpret_cast<uint4*>(u1) = *reinterpret_cast<const uint4*>(&pO1[(size_t)gi * HV + col]);
  ushort4 w[2];
  #pragma unroll
  for (int q = 0; q < 2; ++q) {
    w[q].x = f2bf(bf2f(u0[q].x) * f0 + bf2f(u1[q].x) * f1);
    w[q].y = f2bf(bf2f(u0[q].y) * f0 + bf2f(u1[q].y) * f1);
    w[q].z = f2bf(bf2f(u0[q].z) * f0 + bf2f(u1[q].z) * f1);
    w[q].w = f2bf(bf2f(u0[q].w) * f0 + bf2f(u1[q].w) * f1);
  }
  *reinterpret_cast<uint4*>(&pO0[(size_t)gi * HV + col]) = *reinterpret_cast<uint4*>(w);
}

// ---------------------------------------------------------------------------
extern "C" void kernel_launch(void* const* d_in, const int* in_sizes, int n_in,
                              void* d_out, int out_size, void* d_ws, size_t ws_size,
                              hipStream_t stream) {
  const float* x   = (const float*)d_in[0];
  const float* Wq  = (const float*)d_in[1];
  const float* Wk  = (const float*)d_in[2];
  const float* Wv  = (const float*)d_in[3];
  const float* Wrk = (const float*)d_in[4];
  const float* rwb = (const float*)d_in[5];
  const float* rrb = (const float*)d_in[6];
  const float* Wo  = (const float*)d_in[7];
  const float* bo  = (const float*)d_in[8];
  float* out = (float*)d_out;

  const int BT = 2 * T_SEQ;   // 3072

  // Workspace: 53,476,352 B (== R9 proven footprint). Reuse at attn time:
  // pO0 = xb (x dead), pO1 = vb (dead after vtrans), ml0/ml1 = Wqt/Wkt
  // regions (dead after QKV GEMM). Merge writes ab in-place over pO0.
  char* w = (char*)d_ws;
  float* qf            = (float*)w;          w += (size_t)BT * HK * 4;
  unsigned short* kbuf = (unsigned short*)w; w += (size_t)BT * HK * 2;
  unsigned short* vb   = (unsigned short*)w; w += (size_t)BT * HV * 2;
  unsigned short* vtb  = (unsigned short*)w; w += (size_t)2 * HV * T_SEQ * 2;
  unsigned short* rkb  = (unsigned short*)w; w += (size_t)HEADS * RWIN * DK * 2;
  unsigned short* xb   = (unsigned short*)w; w += (size_t)BT * CDIM * 2;
  unsigned short* Wqt  = (unsigned short*)w; w += (size_t)HK * CDIM * 2;
  unsigned short* Wkt  = (unsigned short*)w; w += (size_t)HK * CDIM * 2;
  unsigned short* Wvt  = (unsigned short*)w; w += (size_t)HV * CDIM * 2;
  unsigned short* Wot  = (unsigned short*)w; w += (size_t)HV * CDIM * 2;

  unsigned short* pO0 = xb;           // attn partial 0 / final ab
  unsigned short* pO1 = vb;           // attn partial 1
  float2* ml0 = (float2*)Wqt;         // 3072*8*8B = 196 KB
  float2* ml1 = (float2*)Wkt;

  const int nx = BT * CDIM;

  cast_bf16_kernel<<<nx / 1024, 256, 0, stream>>>(x, xb, nx);
  tcast_kernel<<<dim3(HK / 32, CDIM / 32), dim3(32, 8), 0, stream>>>(Wq, Wqt, CDIM, HK);
  tcast_kernel<<<dim3(HK / 32, CDIM / 32), dim3(32, 8), 0, stream>>>(Wk, Wkt, CDIM, HK);
  tcast_kernel<<<dim3(HV / 32, CDIM / 32), dim3(32, 8), 0, stream>>>(Wv, Wvt, CDIM, HV);
  tcast_kernel<<<dim3(HV / 32, CDIM / 32), dim3(32, 8), 0, stream>>>(Wo, Wot, CDIM, HV);

  // fused QKV (Bt = Wqt|Wkt|Wvt contiguous, N=2560 -> 480 blocks)
  gemm_qkv_kernel<<<dim3(BT / 128, (2 * HK + HV) / 128), 256, 0, stream>>>(
      xb, Wqt, qf, kbuf, vb, BT, CDIM);

  vtrans_kernel<<<dim3(HV / 32, T_SEQ / 32, 2), dim3(32, 8), 0, stream>>>(vb, vtb);
  rk_kernel<<<RWIN, 512, 0, stream>>>(Wrk, rkb);

  attn_mfma_kernel<<<768, 256, 0, stream>>>(
      qf, kbuf, vtb, rkb, rwb, rrb, pO0, pO1, ml0, ml1);

  merge_kernel<<<BT, 192, 0, stream>>>(pO0, pO1, ml0, ml1);

  gemm_bf16_kernel<<<dim3(BT / 128, HV / 128), 256, 0, stream>>>(
      pO0, Wot, out, BT, HV, CDIM, 1.0f, bo);
}